// Round 1
// baseline (160.148 us; speedup 1.0000x reference)
//
#include <hip/hip_runtime.h>
#include <math.h>

#define N_NODES 10000
#define N_EDGES 320000
#define F_IN 512
#define HID 256
#define PAD_DEG 80    // max in-degree ~60 (Poisson(32) over 10k nodes); 80 is +8.5 sigma
#define LDSTR 40      // LDS row stride in halves (32 + 8 pad, keeps 16B alignment)
#define N_GTILES 158  // 79 row-tiles x 2 col-tiles of 128x128
#define BUILD_BLKS ((N_EDGES + 255) / 256)   // 1250

typedef _Float16 half8 __attribute__((ext_vector_type(8)));
typedef float floatx4 __attribute__((ext_vector_type(4)));

__device__ __forceinline__ void fma4(float4& acc, float s, const float4& v) {
    acc.x += s * v.x; acc.y += s * v.y; acc.z += s * v.z; acc.w += s * v.w;
}

// ---- k_pre: zero degree counters + W1 [512][256] -> transposed fp16 hi/lo split ----
// grid 512x256 = 131072 threads = F_IN*HID exactly.

__global__ __launch_bounds__(256) void k_pre(const float* __restrict__ W1,
                                             int* __restrict__ count,
                                             _Float16* __restrict__ Bt_hi,
                                             _Float16* __restrict__ Bt_lo) {
    int i = blockIdx.x * blockDim.x + threadIdx.x;
    if (i < 10240) count[i] = 0;
    int k = i >> 8, n = i & 255;
    float v = W1[i];
    _Float16 hi = (_Float16)v;
    Bt_hi[n * F_IN + k] = hi;
    Bt_lo[n * F_IN + k] = (_Float16)(v - (float)hi);
}

// ---- k_combo: GEMM 128x128 tiles (blocks 0..157) || CSR build (blocks 158..1407) ----
// 128x128 tile: A panel read once per row-tile (vs 4x at 64x64), LDS reads/MFMA halved.

__global__ __launch_bounds__(256) void k_combo(const float* __restrict__ A,
                                               const _Float16* __restrict__ Bt_hi,
                                               const _Float16* __restrict__ Bt_lo,
                                               const float* __restrict__ b1,
                                               float* __restrict__ h0,
                                               const int* __restrict__ ei,
                                               int* __restrict__ count,
                                               int* __restrict__ csr) {
    __shared__ _Float16 As_hi[128 * LDSTR], As_lo[128 * LDSTR];
    __shared__ _Float16 Bs_hi[128 * LDSTR], Bs_lo[128 * LDSTR];
    const int tid = threadIdx.x;

    if (blockIdx.x >= N_GTILES) {
        // ---------- CSR build half ----------
        int e = (blockIdx.x - N_GTILES) * 256 + tid;
        if (e < N_EDGES) {
            int src = ei[e];
            int dst = ei[N_EDGES + e];
            int pos = atomicAdd(&count[dst], 1);   // final value = in-degree
            csr[dst * PAD_DEG + pos] = src;
        }
        return;
    }

    // ---------- GEMM half: h0 = feature @ W1 + b1, 3-term fp16-split MFMA ----------
    const int lane = tid & 63, w = tid >> 6;
    const int wm = (w >> 1) * 64, wn = (w & 1) * 64;   // wave = 64x64 sub-tile
    const int quad = lane >> 4, l15 = lane & 15;
    const int r = tid >> 1, c = (tid & 1) << 4;        // stage 128 rows x 32 halves
    const int t = blockIdx.x;
    const int row0 = (t >> 1) * 128, col0 = (t & 1) * 128;
    floatx4 acc[4][4] = {};

    const int arow = row0 + r;
    const float* Aptr = A + (size_t)arow * F_IN + c;
    const _Float16* Bh = Bt_hi + (size_t)(col0 + r) * F_IN + c;
    const _Float16* Bl = Bt_lo + (size_t)(col0 + r) * F_IN + c;

    for (int k0 = 0; k0 < F_IN; k0 += 32) {
        float av[16];
        if (arow < N_NODES) {
            #pragma unroll
            for (int q = 0; q < 4; ++q) {
                float4 v = *(const float4*)(Aptr + k0 + q * 4);
                av[q * 4 + 0] = v.x; av[q * 4 + 1] = v.y;
                av[q * 4 + 2] = v.z; av[q * 4 + 3] = v.w;
            }
        } else {
            #pragma unroll
            for (int i = 0; i < 16; ++i) av[i] = 0.f;
        }
        half8 hhi[2], hlo[2];
        #pragma unroll
        for (int i = 0; i < 16; ++i) {
            _Float16 h = (_Float16)av[i];
            hhi[i >> 3][i & 7] = h;
            hlo[i >> 3][i & 7] = (_Float16)(av[i] - (float)h);
        }
        *(half8*)&As_hi[r * LDSTR + c]     = hhi[0];
        *(half8*)&As_hi[r * LDSTR + c + 8] = hhi[1];
        *(half8*)&As_lo[r * LDSTR + c]     = hlo[0];
        *(half8*)&As_lo[r * LDSTR + c + 8] = hlo[1];
        *(half8*)&Bs_hi[r * LDSTR + c]     = *(const half8*)(Bh + k0);
        *(half8*)&Bs_hi[r * LDSTR + c + 8] = *(const half8*)(Bh + k0 + 8);
        *(half8*)&Bs_lo[r * LDSTR + c]     = *(const half8*)(Bl + k0);
        *(half8*)&Bs_lo[r * LDSTR + c + 8] = *(const half8*)(Bl + k0 + 8);
        __syncthreads();
        half8 a_hi[4], a_lo[4];
        #pragma unroll
        for (int mi = 0; mi < 4; ++mi) {
            int mr = wm + mi * 16 + l15;             // A[m=lane&15][k=quad*8+j]
            a_hi[mi] = *(half8*)&As_hi[mr * LDSTR + quad * 8];
            a_lo[mi] = *(half8*)&As_lo[mr * LDSTR + quad * 8];
        }
        #pragma unroll
        for (int ni = 0; ni < 4; ++ni) {
            int nr = wn + ni * 16 + l15;             // B[k][n] from transposed tile
            half8 b_hi = *(half8*)&Bs_hi[nr * LDSTR + quad * 8];
            half8 b_lo = *(half8*)&Bs_lo[nr * LDSTR + quad * 8];
            #pragma unroll
            for (int mi = 0; mi < 4; ++mi) {
                acc[mi][ni] = __builtin_amdgcn_mfma_f32_16x16x32_f16(a_hi[mi], b_hi, acc[mi][ni], 0, 0, 0);
                acc[mi][ni] = __builtin_amdgcn_mfma_f32_16x16x32_f16(a_hi[mi], b_lo, acc[mi][ni], 0, 0, 0);
                acc[mi][ni] = __builtin_amdgcn_mfma_f32_16x16x32_f16(a_lo[mi], b_hi, acc[mi][ni], 0, 0, 0);
            }
        }
        __syncthreads();
    }
    // epilogue: C/D layout col=lane&15, row=quad*4+reg
    #pragma unroll
    for (int mi = 0; mi < 4; ++mi)
        #pragma unroll
        for (int ni = 0; ni < 4; ++ni) {
            int colb = col0 + wn + ni * 16 + l15;
            float bias = b1[colb];
            #pragma unroll
            for (int reg = 0; reg < 4; ++reg) {
                int rowb = row0 + wm + mi * 16 + quad * 4 + reg;
                if (rowb < N_NODES) h0[(size_t)rowb * HID + colb] = acc[mi][ni][reg] + bias;
            }
        }
}

// ---- k_agg1: u0 = relu(agg(h0)) @ W2 + b2 ----
// one wave/node. NEW: neighbor list + rsqrt weights preloaded IN PARALLEL (lanes) into
// LDS, so the inner loop is 8 independent broadcast ds_read_b64 + 8 independent 1KB
// coalesced gathers per iteration — no serial row[]/count[] dependency chain.

__global__ __launch_bounds__(256) void k_agg1(const float* __restrict__ h0,
                                              const int* __restrict__ csr,
                                              const int* __restrict__ count,
                                              const float* __restrict__ W2,
                                              const float* __restrict__ b2,
                                              float* __restrict__ u0) {
    __shared__ int2 nb[4][PAD_DEG];                   // {src, weight-bits} per wave
    const int wid = threadIdx.x >> 6;
    const int lane = threadIdx.x & 63;
    const int n = blockIdx.x * 4 + wid;               // grid = 2500 -> n < 10000 always
    const int deg = count[n];
    const float degd = (float)(deg > 0 ? deg : 1);
    const int* row = csr + (size_t)n * PAD_DEG;
    for (int j = lane; j < deg; j += 64) {            // parallel preload (deg <= 80)
        int s = row[j];
        int cs = count[s];
        float wq = rsqrtf((float)(cs > 0 ? cs : 1) * degd);
        nb[wid][j] = make_int2(s, __float_as_int(wq));
    }
    __syncthreads();                                  // all waves reach (no early return)

    const int off = lane << 2;
    float4 acc0 = {0,0,0,0}, acc1 = {0,0,0,0}, acc2 = {0,0,0,0}, acc3 = {0,0,0,0};
    int j = 0;
    for (; j + 8 <= deg; j += 8) {
        int2 e0 = nb[wid][j+0], e1 = nb[wid][j+1], e2 = nb[wid][j+2], e3 = nb[wid][j+3];
        int2 e4 = nb[wid][j+4], e5 = nb[wid][j+5], e6 = nb[wid][j+6], e7 = nb[wid][j+7];
        float4 v0 = *(const float4*)(h0 + ((size_t)e0.x << 8) + off);
        float4 v1 = *(const float4*)(h0 + ((size_t)e1.x << 8) + off);
        float4 v2 = *(const float4*)(h0 + ((size_t)e2.x << 8) + off);
        float4 v3 = *(const float4*)(h0 + ((size_t)e3.x << 8) + off);
        float4 v4 = *(const float4*)(h0 + ((size_t)e4.x << 8) + off);
        float4 v5 = *(const float4*)(h0 + ((size_t)e5.x << 8) + off);
        float4 v6 = *(const float4*)(h0 + ((size_t)e6.x << 8) + off);
        float4 v7 = *(const float4*)(h0 + ((size_t)e7.x << 8) + off);
        fma4(acc0, __int_as_float(e0.y), v0);
        fma4(acc1, __int_as_float(e1.y), v1);
        fma4(acc2, __int_as_float(e2.y), v2);
        fma4(acc3, __int_as_float(e3.y), v3);
        fma4(acc0, __int_as_float(e4.y), v4);
        fma4(acc1, __int_as_float(e5.y), v5);
        fma4(acc2, __int_as_float(e6.y), v6);
        fma4(acc3, __int_as_float(e7.y), v7);
    }
    for (; j < deg; ++j) {
        int2 e = nb[wid][j];
        float4 v = *(const float4*)(h0 + ((size_t)e.x << 8) + off);
        fma4(acc0, __int_as_float(e.y), v);
    }
    acc0.x += acc1.x + acc2.x + acc3.x;
    acc0.y += acc1.y + acc2.y + acc3.y;
    acc0.z += acc1.z + acc2.z + acc3.z;
    acc0.w += acc1.w + acc2.w + acc3.w;
    acc0.x = fmaxf(acc0.x, 0.f); acc0.y = fmaxf(acc0.y, 0.f);
    acc0.z = fmaxf(acc0.z, 0.f); acc0.w = fmaxf(acc0.w, 0.f);
    float4 wa = *(const float4*)(W2 + (lane << 3));
    float4 wb = *(const float4*)(W2 + (lane << 3) + 4);
    float p0 = acc0.x * wa.x + acc0.y * wa.z + acc0.z * wb.x + acc0.w * wb.z;
    float p1 = acc0.x * wa.y + acc0.y * wa.w + acc0.z * wb.y + acc0.w * wb.w;
    #pragma unroll
    for (int o = 32; o > 0; o >>= 1) {
        p0 += __shfl_down(p0, o);
        p1 += __shfl_down(p1, o);
    }
    if (lane == 0) {
        u0[2 * n]     = p0 + b2[0];
        u0[2 * n + 1] = p1 + b2[1];
    }
}

// ---- k_agg2: second aggregation + Lorentz->Poincare pointwise (weights inline) ----

__global__ __launch_bounds__(256) void k_agg2(const float* __restrict__ u0,
                                              const int* __restrict__ csr,
                                              const int* __restrict__ count,
                                              const float* __restrict__ scale,
                                              float* __restrict__ out) {
    int n = blockIdx.x * 4 + (threadIdx.x >> 6);
    int lane = threadIdx.x & 63;
    if (n >= N_NODES) return;
    int deg = count[n];
    float degd = (float)(deg > 0 ? deg : 1);
    const int* row = csr + (size_t)n * PAD_DEG;
    float a0 = 0.f, a1 = 0.f;
    for (int j = lane; j < deg; j += 64) {
        int s = row[j];
        int cs = count[s];
        float wq = rsqrtf((float)(cs > 0 ? cs : 1) * degd);
        float2 uv = *(const float2*)(u0 + 2 * (size_t)s);
        a0 += wq * uv.x;
        a1 += wq * uv.y;
    }
    #pragma unroll
    for (int o = 32; o > 0; o >>= 1) {
        a0 += __shfl_down(a0, o);
        a1 += __shfl_down(a1, o);
    }
    if (lane == 0) {
        float un = fmaxf(sqrtf(a0 * a0 + a1 * a1), 1e-15f);
        float t = tanhf(0.5f * un) / un;   // sinh/(1+cosh)==tanh(x/2), overflow-proof
        float p0 = a0 * t, p1 = a1 * t;
        float pn = fmaxf(sqrtf(p0 * p0 + p1 * p1), 1e-12f);
        float s = fminf(fmaxf(scale[0], 0.666f), 0.999f);
        p0 = p0 / pn * s; p1 = p1 / pn * s;
        float nn = fmaxf(sqrtf(p0 * p0 + p1 * p1), 1e-15f);
        if (nn > 1.0f) { p0 = p0 / nn; p1 = p1 / nn; }   // (1-1e-15)==1.0f in fp32
        out[2 * n]     = p0;
        out[2 * n + 1] = p1;
    }
}

// ---------------- launch ----------------

extern "C" void kernel_launch(void* const* d_in, const int* in_sizes, int n_in,
                              void* d_out, int out_size, void* d_ws, size_t ws_size,
                              hipStream_t stream) {
    const float* feature = (const float*)d_in[0];
    const int*   ei      = (const int*)d_in[1];
    const float* W1      = (const float*)d_in[2];
    const float* b1      = (const float*)d_in[3];
    const float* W2      = (const float*)d_in[4];
    const float* b2      = (const float*)d_in[5];
    const float* scale   = (const float*)d_in[6];
    float* out = (float*)d_out;

    // workspace layout (byte offsets, all 16B-aligned)
    char* W = (char*)d_ws;
    int*      count = (int*)W;                    // 10240 ints
    int*      csr   = (int*)(W + 40960);          // 800000 ints
    float*    h0    = (float*)(W + 3240960);      // 10000*256 fp32
    float*    u0    = (float*)(W + 13480960);     // 20000 floats
    _Float16* Bt_hi = (_Float16*)(W + 13560960);  // 256*512 halves
    _Float16* Bt_lo = (_Float16*)(W + 13823104);  // 256*512 halves  (~14.1 MB total)

    k_pre<<<dim3(512), dim3(256), 0, stream>>>(W1, count, Bt_hi, Bt_lo);
    k_combo<<<dim3(N_GTILES + BUILD_BLKS), dim3(256), 0, stream>>>(
        feature, Bt_hi, Bt_lo, b1, h0, ei, count, csr);
    k_agg1<<<dim3((N_NODES + 3) / 4), dim3(256), 0, stream>>>(h0, csr, count, W2, b2, u0);
    k_agg2<<<dim3((N_NODES + 3) / 4), dim3(256), 0, stream>>>(u0, csr, count, scale, out);
}

// Round 2
// 150.322 us; speedup vs baseline: 1.0654x; 1.0654x over previous
//
#include <hip/hip_runtime.h>
#include <math.h>

#define N_NODES 10000
#define N_EDGES 320000
#define F_IN 512
#define HID 256
#define PAD_DEG 80    // max in-degree ~60 (Poisson(32) over 10k nodes); 80 is +8.5 sigma
#define LDSTR 40      // LDS row stride in halves (32 + 8 pad, keeps 16B alignment)
#define N_GTILES 158  // 79 row-tiles x 2 col-tiles of 128x128
#define BUILD_BLKS ((N_EDGES + 255) / 256)   // 1250

typedef _Float16 half8 __attribute__((ext_vector_type(8)));
typedef float floatx4 __attribute__((ext_vector_type(4)));

__device__ __forceinline__ void fma4(float4& acc, float s, const float4& v) {
    acc.x += s * v.x; acc.y += s * v.y; acc.z += s * v.z; acc.w += s * v.w;
}

// ---- k_pre: zero degree counters + W1 [512][256] -> transposed fp16 hi/lo split ----

__global__ __launch_bounds__(256) void k_pre(const float* __restrict__ W1,
                                             int* __restrict__ count,
                                             _Float16* __restrict__ Bt_hi,
                                             _Float16* __restrict__ Bt_lo) {
    int i = blockIdx.x * blockDim.x + threadIdx.x;
    if (i < 10240) count[i] = 0;
    int k = i >> 8, n = i & 255;
    float v = W1[i];
    _Float16 hi = (_Float16)v;
    Bt_hi[n * F_IN + k] = hi;
    Bt_lo[n * F_IN + k] = (_Float16)(v - (float)hi);
}

// ---- k_combo: GEMM 128x128 tiles (blocks 0..157) || CSR build (blocks 158..1407) ----
// NEW this round: double-buffered LDS + register prefetch software pipeline,
// ONE barrier per k-iter. Global loads for k+1 are in flight across the barrier
// and land under the 48-MFMA compute phase -> latency no longer exposed.

__global__ __launch_bounds__(256) void k_combo(const float* __restrict__ A,
                                               const _Float16* __restrict__ Bt_hi,
                                               const _Float16* __restrict__ Bt_lo,
                                               const float* __restrict__ b1,
                                               float* __restrict__ h0,
                                               const int* __restrict__ ei,
                                               int* __restrict__ count,
                                               int* __restrict__ csr) {
    __shared__ _Float16 As_hi[2][128 * LDSTR], As_lo[2][128 * LDSTR];
    __shared__ _Float16 Bs_hi[2][128 * LDSTR], Bs_lo[2][128 * LDSTR];   // 81920 B total
    const int tid = threadIdx.x;

    if (blockIdx.x >= N_GTILES) {
        // ---------- CSR build half ----------
        int e = (blockIdx.x - N_GTILES) * 256 + tid;
        if (e < N_EDGES) {
            int src = ei[e];
            int dst = ei[N_EDGES + e];
            int pos = atomicAdd(&count[dst], 1);   // final value = in-degree
            csr[dst * PAD_DEG + pos] = src;
        }
        return;
    }

    // ---------- GEMM half: h0 = feature @ W1 + b1, 3-term fp16-split MFMA ----------
    const int lane = tid & 63, w = tid >> 6;
    const int wm = (w >> 1) * 64, wn = (w & 1) * 64;   // wave = 64x64 sub-tile
    const int quad = lane >> 4, l15 = lane & 15;
    const int r = tid >> 1, c = (tid & 1) << 4;        // stage 128 rows x 32 halves
    const int t = blockIdx.x;
    const int row0 = (t >> 1) * 128, col0 = (t & 1) * 128;
    floatx4 acc[4][4] = {};

    const int arow = row0 + r;
    const bool aval = arow < N_NODES;
    const float* Aptr = A + (size_t)arow * F_IN + c;
    const _Float16* Bh = Bt_hi + (size_t)(col0 + r) * F_IN + c;
    const _Float16* Bl = Bt_lo + (size_t)(col0 + r) * F_IN + c;

    // register prefetch state (k-slice staged by this thread: 16 A floats, 2x B half8)
    float4 apf[4] = {{0,0,0,0},{0,0,0,0},{0,0,0,0},{0,0,0,0}};
    half8 bhpf[2], blpf[2];

    // prologue: load k0 = 0
    if (aval) {
        #pragma unroll
        for (int q = 0; q < 4; ++q) apf[q] = *(const float4*)(Aptr + q * 4);
    }
    bhpf[0] = *(const half8*)(Bh);     bhpf[1] = *(const half8*)(Bh + 8);
    blpf[0] = *(const half8*)(Bl);     blpf[1] = *(const half8*)(Bl + 8);

    int buf = 0;
    for (int k0 = 0; k0 < F_IN; k0 += 32) {
        // ---- stage current k-slice from regs into LDS[buf] ----
        float av[16];
        #pragma unroll
        for (int q = 0; q < 4; ++q) {
            av[4 * q + 0] = apf[q].x; av[4 * q + 1] = apf[q].y;
            av[4 * q + 2] = apf[q].z; av[4 * q + 3] = apf[q].w;
        }
        half8 hhi[2], hlo[2];
        #pragma unroll
        for (int i = 0; i < 16; ++i) {
            _Float16 h = (_Float16)av[i];
            hhi[i >> 3][i & 7] = h;
            hlo[i >> 3][i & 7] = (_Float16)(av[i] - (float)h);
        }
        *(half8*)&As_hi[buf][r * LDSTR + c]     = hhi[0];
        *(half8*)&As_hi[buf][r * LDSTR + c + 8] = hhi[1];
        *(half8*)&As_lo[buf][r * LDSTR + c]     = hlo[0];
        *(half8*)&As_lo[buf][r * LDSTR + c + 8] = hlo[1];
        *(half8*)&Bs_hi[buf][r * LDSTR + c]     = bhpf[0];
        *(half8*)&Bs_hi[buf][r * LDSTR + c + 8] = bhpf[1];
        *(half8*)&Bs_lo[buf][r * LDSTR + c]     = blpf[0];
        *(half8*)&Bs_lo[buf][r * LDSTR + c + 8] = blpf[1];

        // ---- issue next k-slice global loads (in flight across the barrier) ----
        if (k0 + 32 < F_IN) {
            if (aval) {
                #pragma unroll
                for (int q = 0; q < 4; ++q)
                    apf[q] = *(const float4*)(Aptr + k0 + 32 + q * 4);
            }
            bhpf[0] = *(const half8*)(Bh + k0 + 32);
            bhpf[1] = *(const half8*)(Bh + k0 + 40);
            blpf[0] = *(const half8*)(Bl + k0 + 32);
            blpf[1] = *(const half8*)(Bl + k0 + 40);
        }

        __syncthreads();

        // ---- compute from LDS[buf] ----
        half8 a_hi[4], a_lo[4];
        #pragma unroll
        for (int mi = 0; mi < 4; ++mi) {
            int mr = wm + mi * 16 + l15;             // A[m=lane&15][k=quad*8+j]
            a_hi[mi] = *(half8*)&As_hi[buf][mr * LDSTR + quad * 8];
            a_lo[mi] = *(half8*)&As_lo[buf][mr * LDSTR + quad * 8];
        }
        #pragma unroll
        for (int ni = 0; ni < 4; ++ni) {
            int nr = wn + ni * 16 + l15;             // B[k][n] from transposed tile
            half8 b_hi = *(half8*)&Bs_hi[buf][nr * LDSTR + quad * 8];
            half8 b_lo = *(half8*)&Bs_lo[buf][nr * LDSTR + quad * 8];
            #pragma unroll
            for (int mi = 0; mi < 4; ++mi) {
                acc[mi][ni] = __builtin_amdgcn_mfma_f32_16x16x32_f16(a_hi[mi], b_hi, acc[mi][ni], 0, 0, 0);
                acc[mi][ni] = __builtin_amdgcn_mfma_f32_16x16x32_f16(a_hi[mi], b_lo, acc[mi][ni], 0, 0, 0);
                acc[mi][ni] = __builtin_amdgcn_mfma_f32_16x16x32_f16(a_lo[mi], b_hi, acc[mi][ni], 0, 0, 0);
            }
        }
        // no trailing barrier: next iter writes LDS[buf^1]; any wave still reading
        // LDS[buf^1] finished those reads before the barrier above (prog. order).
        buf ^= 1;
    }
    // epilogue: C/D layout col=lane&15, row=quad*4+reg
    #pragma unroll
    for (int mi = 0; mi < 4; ++mi)
        #pragma unroll
        for (int ni = 0; ni < 4; ++ni) {
            int colb = col0 + wn + ni * 16 + l15;
            float bias = b1[colb];
            #pragma unroll
            for (int reg = 0; reg < 4; ++reg) {
                int rowb = row0 + wm + mi * 16 + quad * 4 + reg;
                if (rowb < N_NODES) h0[(size_t)rowb * HID + colb] = acc[mi][ni][reg] + bias;
            }
        }
}

// ---- k_agg1: u0 = relu(agg(h0)) @ W2 + b2 ----
// one wave/node; neighbor list + rsqrt weights preloaded in parallel into LDS;
// inner loop = 8 independent LDS broadcasts + 8 independent 1KB coalesced gathers.

__global__ __launch_bounds__(256) void k_agg1(const float* __restrict__ h0,
                                              const int* __restrict__ csr,
                                              const int* __restrict__ count,
                                              const float* __restrict__ W2,
                                              const float* __restrict__ b2,
                                              float* __restrict__ u0) {
    __shared__ int2 nb[4][PAD_DEG];                   // {src, weight-bits} per wave
    const int wid = threadIdx.x >> 6;
    const int lane = threadIdx.x & 63;
    const int n = blockIdx.x * 4 + wid;               // grid = 2500 -> n < 10000 always
    const int deg = count[n];
    const float degd = (float)(deg > 0 ? deg : 1);
    const int* row = csr + (size_t)n * PAD_DEG;
    for (int j = lane; j < deg; j += 64) {            // parallel preload (deg <= 80)
        int s = row[j];
        int cs = count[s];
        float wq = rsqrtf((float)(cs > 0 ? cs : 1) * degd);
        nb[wid][j] = make_int2(s, __float_as_int(wq));
    }
    __syncthreads();                                  // all waves reach (no early return)

    const int off = lane << 2;
    float4 acc0 = {0,0,0,0}, acc1 = {0,0,0,0}, acc2 = {0,0,0,0}, acc3 = {0,0,0,0};
    int j = 0;
    for (; j + 8 <= deg; j += 8) {
        int2 e0 = nb[wid][j+0], e1 = nb[wid][j+1], e2 = nb[wid][j+2], e3 = nb[wid][j+3];
        int2 e4 = nb[wid][j+4], e5 = nb[wid][j+5], e6 = nb[wid][j+6], e7 = nb[wid][j+7];
        float4 v0 = *(const float4*)(h0 + ((size_t)e0.x << 8) + off);
        float4 v1 = *(const float4*)(h0 + ((size_t)e1.x << 8) + off);
        float4 v2 = *(const float4*)(h0 + ((size_t)e2.x << 8) + off);
        float4 v3 = *(const float4*)(h0 + ((size_t)e3.x << 8) + off);
        float4 v4 = *(const float4*)(h0 + ((size_t)e4.x << 8) + off);
        float4 v5 = *(const float4*)(h0 + ((size_t)e5.x << 8) + off);
        float4 v6 = *(const float4*)(h0 + ((size_t)e6.x << 8) + off);
        float4 v7 = *(const float4*)(h0 + ((size_t)e7.x << 8) + off);
        fma4(acc0, __int_as_float(e0.y), v0);
        fma4(acc1, __int_as_float(e1.y), v1);
        fma4(acc2, __int_as_float(e2.y), v2);
        fma4(acc3, __int_as_float(e3.y), v3);
        fma4(acc0, __int_as_float(e4.y), v4);
        fma4(acc1, __int_as_float(e5.y), v5);
        fma4(acc2, __int_as_float(e6.y), v6);
        fma4(acc3, __int_as_float(e7.y), v7);
    }
    for (; j < deg; ++j) {
        int2 e = nb[wid][j];
        float4 v = *(const float4*)(h0 + ((size_t)e.x << 8) + off);
        fma4(acc0, __int_as_float(e.y), v);
    }
    acc0.x += acc1.x + acc2.x + acc3.x;
    acc0.y += acc1.y + acc2.y + acc3.y;
    acc0.z += acc1.z + acc2.z + acc3.z;
    acc0.w += acc1.w + acc2.w + acc3.w;
    acc0.x = fmaxf(acc0.x, 0.f); acc0.y = fmaxf(acc0.y, 0.f);
    acc0.z = fmaxf(acc0.z, 0.f); acc0.w = fmaxf(acc0.w, 0.f);
    float4 wa = *(const float4*)(W2 + (lane << 3));
    float4 wb = *(const float4*)(W2 + (lane << 3) + 4);
    float p0 = acc0.x * wa.x + acc0.y * wa.z + acc0.z * wb.x + acc0.w * wb.z;
    float p1 = acc0.x * wa.y + acc0.y * wa.w + acc0.z * wb.y + acc0.w * wb.w;
    #pragma unroll
    for (int o = 32; o > 0; o >>= 1) {
        p0 += __shfl_down(p0, o);
        p1 += __shfl_down(p1, o);
    }
    if (lane == 0) {
        u0[2 * n]     = p0 + b2[0];
        u0[2 * n + 1] = p1 + b2[1];
    }
}

// ---- k_agg2: second aggregation + Lorentz->Poincare pointwise (weights inline) ----

__global__ __launch_bounds__(256) void k_agg2(const float* __restrict__ u0,
                                              const int* __restrict__ csr,
                                              const int* __restrict__ count,
                                              const float* __restrict__ scale,
                                              float* __restrict__ out) {
    int n = blockIdx.x * 4 + (threadIdx.x >> 6);
    int lane = threadIdx.x & 63;
    if (n >= N_NODES) return;
    int deg = count[n];
    float degd = (float)(deg > 0 ? deg : 1);
    const int* row = csr + (size_t)n * PAD_DEG;
    float a0 = 0.f, a1 = 0.f;
    for (int j = lane; j < deg; j += 64) {
        int s = row[j];
        int cs = count[s];
        float wq = rsqrtf((float)(cs > 0 ? cs : 1) * degd);
        float2 uv = *(const float2*)(u0 + 2 * (size_t)s);
        a0 += wq * uv.x;
        a1 += wq * uv.y;
    }
    #pragma unroll
    for (int o = 32; o > 0; o >>= 1) {
        a0 += __shfl_down(a0, o);
        a1 += __shfl_down(a1, o);
    }
    if (lane == 0) {
        float un = fmaxf(sqrtf(a0 * a0 + a1 * a1), 1e-15f);
        float t = tanhf(0.5f * un) / un;   // sinh/(1+cosh)==tanh(x/2), overflow-proof
        float p0 = a0 * t, p1 = a1 * t;
        float pn = fmaxf(sqrtf(p0 * p0 + p1 * p1), 1e-12f);
        float s = fminf(fmaxf(scale[0], 0.666f), 0.999f);
        p0 = p0 / pn * s; p1 = p1 / pn * s;
        float nn = fmaxf(sqrtf(p0 * p0 + p1 * p1), 1e-15f);
        if (nn > 1.0f) { p0 = p0 / nn; p1 = p1 / nn; }   // (1-1e-15)==1.0f in fp32
        out[2 * n]     = p0;
        out[2 * n + 1] = p1;
    }
}

// ---------------- launch ----------------

extern "C" void kernel_launch(void* const* d_in, const int* in_sizes, int n_in,
                              void* d_out, int out_size, void* d_ws, size_t ws_size,
                              hipStream_t stream) {
    const float* feature = (const float*)d_in[0];
    const int*   ei      = (const int*)d_in[1];
    const float* W1      = (const float*)d_in[2];
    const float* b1      = (const float*)d_in[3];
    const float* W2      = (const float*)d_in[4];
    const float* b2      = (const float*)d_in[5];
    const float* scale   = (const float*)d_in[6];
    float* out = (float*)d_out;

    // workspace layout (byte offsets, all 16B-aligned)
    char* W = (char*)d_ws;
    int*      count = (int*)W;                    // 10240 ints
    int*      csr   = (int*)(W + 40960);          // 800000 ints
    float*    h0    = (float*)(W + 3240960);      // 10000*256 fp32
    float*    u0    = (float*)(W + 13480960);     // 20000 floats
    _Float16* Bt_hi = (_Float16*)(W + 13560960);  // 256*512 halves
    _Float16* Bt_lo = (_Float16*)(W + 13823104);  // 256*512 halves  (~14.1 MB total)

    k_pre<<<dim3(512), dim3(256), 0, stream>>>(W1, count, Bt_hi, Bt_lo);
    k_combo<<<dim3(N_GTILES + BUILD_BLKS), dim3(256), 0, stream>>>(
        feature, Bt_hi, Bt_lo, b1, h0, ei, count, csr);
    k_agg1<<<dim3((N_NODES + 3) / 4), dim3(256), 0, stream>>>(h0, csr, count, W2, b2, u0);
    k_agg2<<<dim3((N_NODES + 3) / 4), dim3(256), 0, stream>>>(u0, csr, count, scale, out);
}